// Round 15
// baseline (42.899 us; speedup 1.0000x reference)
//
#include <hip/hip_runtime.h>

#define HH 128
#define WW 128
#define HWSZ (HH*WW)
#define NB 4
#define KK 9
#define PS (HWSZ*8)          // plane stride in shorts: 16384 px * 8 ch
#define IMS (12*PS)          // image stride in shorts: 12 channel-blocks
#define TROWS 6
#define TCOLS 68
#define TPX (TROWS*TCOLS)    // 408 pixels per staged plane
#define XPLANE (TPX*8 + 16)  // 3280 shorts: +32B so lg planes stagger banks
#define OSTR 40              // offsm stride in shorts (80B, 16B-aligned)

typedef _Float16 half8 __attribute__((ext_vector_type(8)));
typedef _Float16 h2    __attribute__((ext_vector_type(2)));
typedef float f32x4    __attribute__((ext_vector_type(4)));

union U4 { uint4 v; unsigned a[4]; };
union HU { unsigned u; h2 h; };

__device__ __forceinline__ short f2h(float f) {
    union { _Float16 h; short s; } u; u.h = (_Float16)f; return u.s;
}
__device__ __forceinline__ void gl_lds16(const short* g, short* l) {
    __builtin_amdgcn_global_load_lds(
        (const __attribute__((address_space(1))) void*)g,
        (__attribute__((address_space(3))) void*)l, 16, 0, 0);
}
__device__ __forceinline__ void gl_lds4(const float* g, float* l) {
    __builtin_amdgcn_global_load_lds(
        (const __attribute__((address_space(1))) void*)g,
        (__attribute__((address_space(3))) void*)l, 4, 0, 0);
}

// ---------------- prep: channel-block-planar f16 transpose + weight repack ----------------
__global__ __launch_bounds__(256) void prep_kernel(
    const float* __restrict__ input,
    const float* __restrict__ mask_in,
    const float* __restrict__ weight,
    const float* __restrict__ offset_w,
    const float* __restrict__ mask_w,
    short* __restrict__ xt2,
    short* __restrict__ wd2,
    short* __restrict__ wc2)
{
    __shared__ short lds[64 * 104];
    int bid = blockIdx.x;
    if (bid < 1024) {
        int wg = ((bid & 7) << 7) | (bid >> 3);
        int g0 = wg * 64;
        int b  = g0 >> 14;
        int p0 = g0 & (HWSZ - 1);
        int px = threadIdx.x & 63;
        int cq = threadIdx.x >> 6;
#pragma unroll
        for (int it = 0; it < 24; ++it) {
            int c = it * 4 + cq;
            float v;
            if (c < 64)       v = input[((size_t)(b * 64 + c)) * HWSZ + p0 + px];
            else if (c == 64) v = mask_in[(size_t)b * HWSZ + p0 + px];
            else              v = 0.f;
            lds[px * 104 + c] = f2h(v);
        }
        __syncthreads();
#pragma unroll
        for (int it = 0; it < 3; ++it) {
            int idx = it * 256 + threadIdx.x;
            if (idx < 768) {
                int ppx = idx / 12, cb = idx - ppx * 12;
                uint4 v = *(const uint4*)&lds[ppx * 104 + cb * 8];
                *(uint4*)&xt2[(size_t)b * IMS + (size_t)cb * PS + (size_t)(p0 + ppx) * 8] = v;
            }
        }
    } else {
        int idx = (bid - 1024) * 256 + threadIdx.x;
        if (idx < 36864) {
            int j = idx & 7, l = (idx >> 3) & 63, f = idx >> 9;
            int nt = f & 3, t9 = f >> 2;
            int k = t9 % 9, ks = t9 / 9;
            int o = nt * 16 + (l & 15);
            int c = ks * 32 + ((l >> 4) & 3) * 8 + j;
            wd2[idx] = f2h(weight[(o * 64 + c) * 9 + k]);
        }
        if (idx < 27648) {
            int j = idx & 7, l = (idx >> 3) & 63, f = idx >> 9;
            int nt = f & 1, t9 = f >> 1;
            int k = t9 % 9, ks = t9 / 9;
            int o = nt * 16 + (l & 15);
            int c = ks * 32 + ((l >> 4) & 3) * 8 + j;
            float v = 0.f;
            if (c <= 64) {
                if (o < 18)      v = offset_w[(o * 65 + c) * 9 + k];
                else if (o < 27) v = mask_w[((o - 18) * 65 + c) * 9 + k];
            }
            wc2[idx] = f2h(v);
        }
    }
}

// ---------------- fused conv + deform: staging overlapped with conv phase ----------------
__global__ __launch_bounds__(256, 2) void fused_conv_deform(
    const short* __restrict__ xt2, const float* __restrict__ mask_in,
    const half8* __restrict__ wc, const half8* __restrict__ wd,
    const float* __restrict__ offset_b, const float* __restrict__ mask_b,
    const float* __restrict__ bias,
    float* __restrict__ out, float* __restrict__ upd)
{
    __shared__ short xsm[8 * XPLANE];    // 52,480 B (reused as outsm in epilogue)
    __shared__ float msm[TPX];           //  1,632 B
    __shared__ short offsm[128 * OSTR];  // 10,240 B f16 (slots 0..26 used)

    int bid = blockIdx.x;
    int wg = ((bid & 7) << 6) | (bid >> 3);   // 512 blocks, XCD bands of 64
    int w = threadIdx.x >> 6, lane = threadIdx.x & 63;
    int r = lane & 15, lg = lane >> 4;
    int b = wg >> 7;
    int rem = wg & 127;
    int ib = (rem >> 1) * 2;          // row pair base
    int j0b = (rem & 1) * 64;         // column half
    int jw = j0b + w * 16;            // wave's column base
    int jj0 = jw + r;                 // this lane's column

    const short* xg = xt2 + (size_t)b * IMS;
    const short* xq = xg + (size_t)lg * PS;   // planar base (plane lg; +4*PS = ks1; +8*PS = mask)
    const float* mb = mask_in + (size_t)b * HWSZ;

    // ---- Phase 0: issue async staging; do NOT wait yet (drains during conv) ----
#pragma unroll
    for (int cb = 0; cb < 8; ++cb) {
#pragma unroll
        for (int it = 0; it < 2; ++it) {
            int idx = it * 256 + threadIdx.x;
            if (idx < TPX) {
                int tr = idx / TCOLS, tc = idx - tr * TCOLS;
                int rg = min(max(ib - 2 + tr, 0), HH - 1);
                int cg = min(max(j0b - 2 + tc, 0), WW - 1);
                gl_lds16(&xg[(size_t)cb * PS + (size_t)(rg * WW + cg) * 8],
                         &xsm[cb * XPLANE + idx * 8]);
            }
        }
    }
#pragma unroll
    for (int it = 0; it < 2; ++it) {
        int idx = it * 256 + threadIdx.x;
        if (idx < TPX) {
            int tr = idx / TCOLS, tc = idx - tr * TCOLS;
            int rg = min(max(ib - 2 + tr, 0), HH - 1);
            int cg = min(max(j0b - 2 + tc, 0), WW - 1);
            gl_lds4(&mb[rg * WW + cg], &msm[idx]);
        }
    }

    // ---- Phase 1: offset/mask conv, A from GLOBAL planar (overlaps staging) ----
    {
        f32x4 ca00 = {0,0,0,0}, ca01 = {0,0,0,0};   // set0 nt0/nt1
        f32x4 ca10 = {0,0,0,0}, ca11 = {0,0,0,0};   // set1
#pragma unroll
        for (int t = 0; t < 9; ++t) {
            int dr = t / 3 - 1, dc = t % 3 - 1;
            const half8* wck = wc + (t * 2) * 64 + lane;
            half8 Bk0n0 = wck[0],        Bk0n1 = wck[64];
            half8 Bk1n0 = wck[9*2*64],   Bk1n1 = wck[9*2*64 + 64];
            half8 Bk2n0 = wck[18*2*64],  Bk2n1 = wck[18*2*64 + 64];
#pragma unroll
            for (int s = 0; s < 2; ++s) {
                int ii = ib + s + dr, jj = jj0 + dc;
                bool valid = ((unsigned)ii < HH) && ((unsigned)jj < WW);
                int nb = (valid ? ii * WW + jj : 0) * 8;
                union { half8 s8; uint4 u; } A0, A1, A2;
                A0.u = *(const uint4*)(xq + nb);
                A1.u = *(const uint4*)(xq + 4 * PS + nb);
                A2.u = *(const uint4*)(xq + 8 * PS + nb);
                if (!valid) {
                    A0.u.x = 0; A0.u.y = 0; A0.u.z = 0; A0.u.w = 0;
                    A1.u.x = 0; A1.u.y = 0; A1.u.z = 0; A1.u.w = 0;
                    A2.u.x = 0; A2.u.y = 0; A2.u.z = 0; A2.u.w = 0;
                }
                if (s == 0) {
                    ca00 = __builtin_amdgcn_mfma_f32_16x16x32_f16(A0.s8, Bk0n0, ca00, 0, 0, 0);
                    ca01 = __builtin_amdgcn_mfma_f32_16x16x32_f16(A0.s8, Bk0n1, ca01, 0, 0, 0);
                    ca00 = __builtin_amdgcn_mfma_f32_16x16x32_f16(A1.s8, Bk1n0, ca00, 0, 0, 0);
                    ca01 = __builtin_amdgcn_mfma_f32_16x16x32_f16(A1.s8, Bk1n1, ca01, 0, 0, 0);
                    ca00 = __builtin_amdgcn_mfma_f32_16x16x32_f16(A2.s8, Bk2n0, ca00, 0, 0, 0);
                    ca01 = __builtin_amdgcn_mfma_f32_16x16x32_f16(A2.s8, Bk2n1, ca01, 0, 0, 0);
                } else {
                    ca10 = __builtin_amdgcn_mfma_f32_16x16x32_f16(A0.s8, Bk0n0, ca10, 0, 0, 0);
                    ca11 = __builtin_amdgcn_mfma_f32_16x16x32_f16(A0.s8, Bk0n1, ca11, 0, 0, 0);
                    ca10 = __builtin_amdgcn_mfma_f32_16x16x32_f16(A1.s8, Bk1n0, ca10, 0, 0, 0);
                    ca11 = __builtin_amdgcn_mfma_f32_16x16x32_f16(A1.s8, Bk1n1, ca11, 0, 0, 0);
                    ca10 = __builtin_amdgcn_mfma_f32_16x16x32_f16(A2.s8, Bk2n0, ca10, 0, 0, 0);
                    ca11 = __builtin_amdgcn_mfma_f32_16x16x32_f16(A2.s8, Bk2n1, ca11, 0, 0, 0);
                }
            }
        }
        int oc = lane & 15, pr0 = lg * 4;
#pragma unroll
        for (int s = 0; s < 2; ++s) {
            const f32x4& c0 = s ? ca10 : ca00;
            const f32x4& c1 = s ? ca11 : ca01;
#pragma unroll
            for (int rr = 0; rr < 4; ++rr) {
                int px = s * 64 + w * 16 + pr0 + rr;
                offsm[px * OSTR + oc] = f2h(c0[rr] + offset_b[oc]);
                int oc2 = 16 + oc;
                if (oc2 < 18) {
                    offsm[px * OSTR + oc2] = f2h(c1[rr] + offset_b[oc2]);
                } else if (oc2 < 27) {
                    float z = c1[rr] + mask_b[oc2 - 18];
                    offsm[px * OSTR + oc2] = f2h(1.f / (1.f + __expf(-z)));
                }
            }
        }
    }
    asm volatile("s_waitcnt vmcnt(0)" ::: "memory");
    __syncthreads();

    // ---- Phase 2: deformable conv, 2 pixel-sets per wave, B reused across sets ----
    float ov0[28], ov1[28];
#pragma unroll
    for (int s = 0; s < 2; ++s) {
        int px = s * 64 + w * 16 + r;
        float* ov = s ? ov1 : ov0;
        const U4* op = (const U4*)&offsm[px * OSTR];
#pragma unroll
        for (int q4 = 0; q4 < 4; ++q4) {
            U4 t = op[q4];
#pragma unroll
            for (int e = 0; e < 4; ++e) {
                int base = q4 * 8 + e * 2;
                if (base < 28) {
                    HU hu; hu.u = t.a[e];
                    ov[base] = (float)hu.h[0];
                    ov[base + 1] = (float)hu.h[1];
                }
            }
        }
    }

    f32x4 ac00 = {0,0,0,0}, ac01 = {0,0,0,0}, ac02 = {0,0,0,0}, ac03 = {0,0,0,0};
    f32x4 ac10 = {0,0,0,0}, ac11 = {0,0,0,0}, ac12 = {0,0,0,0}, ac13 = {0,0,0,0};
    float um0 = 0.f, um1 = 0.f;

#pragma unroll
    for (int k = 0; k < KK; ++k) {
        const half8* w0 = wd + ((0 * 9 + k) * 4) * 64 + lane;
        const half8* w1 = wd + ((1 * 9 + k) * 4) * 64 + lane;
        half8 B00 = w0[0], B01 = w0[64], B02 = w0[128], B03 = w0[192];
        half8 B10 = w1[0], B11 = w1[64], B12 = w1[128], B13 = w1[192];

#pragma unroll
        for (int s = 0; s < 2; ++s) {
            const float* ov = s ? ov1 : ov0;
            int i = ib + s, j = jj0;
            float dy = ov[2*k], dx = ov[2*k+1], m = ov[18+k];
            float py  = dy + (float)(k / 3 + i - 1);
            float pxx = dx + (float)(k % 3 + j - 1);
            float fy = floorf(py), fx = floorf(pxx);
            float wy = py - fy, wx = pxx - fx;
            int y0 = (int)fy, x0 = (int)fx;
            int y1 = y0 + 1, x1 = x0 + 1;
            bool vy0 = (unsigned)y0 < HH, vy1 = (unsigned)y1 < HH;
            bool vx0 = (unsigned)x0 < WW, vx1 = (unsigned)x1 < WW;
            int yc0 = min(max(y0, 0), HH - 1), yc1 = min(max(y1, 0), HH - 1);
            int xc0 = min(max(x0, 0), WW - 1), xc1 = min(max(x1, 0), WW - 1);
            float r00 = (vy0 && vx0) ? (1.f - wy) * (1.f - wx) : 0.f;
            float r01 = (vy0 && vx1) ? (1.f - wy) * wx : 0.f;
            float r10 = (vy1 && vx0) ? wy * (1.f - wx) : 0.f;
            float r11 = (vy1 && vx1) ? wy * wx : 0.f;

            int tr0 = yc0 - (ib - 2), tr1 = yc1 - (ib - 2);
            int tc0 = xc0 - (j0b - 2), tc1 = xc1 - (j0b - 2);
            bool in00 = ((unsigned)tr0 < (unsigned)TROWS) & ((unsigned)tc0 < (unsigned)TCOLS);
            bool in01 = ((unsigned)tr0 < (unsigned)TROWS) & ((unsigned)tc1 < (unsigned)TCOLS);
            bool in10 = ((unsigned)tr1 < (unsigned)TROWS) & ((unsigned)tc0 < (unsigned)TCOLS);
            bool in11 = ((unsigned)tr1 < (unsigned)TROWS) & ((unsigned)tc1 < (unsigned)TCOLS);
            int trc0 = min(max(tr0, 0), TROWS - 1), trc1 = min(max(tr1, 0), TROWS - 1);
            int tcc0 = min(max(tc0, 0), TCOLS - 1), tcc1 = min(max(tc1, 0), TCOLS - 1);
            int l00 = trc0 * TCOLS + tcc0, l01 = trc0 * TCOLS + tcc1;
            int l10 = trc1 * TCOLS + tcc0, l11 = trc1 * TCOLS + tcc1;

            U4 g00[2], g01[2], g10[2], g11[2];
#pragma unroll
            for (int ks = 0; ks < 2; ++ks) {
                const short* xs = xsm + (size_t)(ks * 4 + lg) * XPLANE;
                g00[ks].v = *(const uint4*)(xs + l00 * 8);
                g01[ks].v = *(const uint4*)(xs + l01 * 8);
                g10[ks].v = *(const uint4*)(xs + l10 * 8);
                g11[ks].v = *(const uint4*)(xs + l11 * 8);
            }
            float m00 = msm[l00], m01 = msm[l01], m10 = msm[l10], m11 = msm[l11];

            if (!__all(in00 & in01 & in10 & in11)) {
                int p00 = yc0 * WW + xc0, p01 = yc0 * WW + xc1;
                int p10 = yc1 * WW + xc0, p11 = yc1 * WW + xc1;
                if (!in00) {
                    g00[0].v = *(const uint4*)(xq + (size_t)p00 * 8);
                    g00[1].v = *(const uint4*)(xq + 4 * PS + (size_t)p00 * 8);
                    m00 = mb[p00];
                }
                if (!in01) {
                    g01[0].v = *(const uint4*)(xq + (size_t)p01 * 8);
                    g01[1].v = *(const uint4*)(xq + 4 * PS + (size_t)p01 * 8);
                    m01 = mb[p01];
                }
                if (!in10) {
                    g10[0].v = *(const uint4*)(xq + (size_t)p10 * 8);
                    g10[1].v = *(const uint4*)(xq + 4 * PS + (size_t)p10 * 8);
                    m10 = mb[p10];
                }
                if (!in11) {
                    g11[0].v = *(const uint4*)(xq + (size_t)p11 * 8);
                    g11[1].v = *(const uint4*)(xq + 4 * PS + (size_t)p11 * 8);
                    m11 = mb[p11];
                }
            }

            float umv = r00 * m00 + r01 * m01 + r10 * m10 + r11 * m11;
            if (s == 0) um0 += umv; else um1 += umv;

            float w00 = r00 * m, w01 = r01 * m, w10 = r10 * m, w11 = r11 * m;
            h2 w00h = { (_Float16)w00, (_Float16)w00 };
            h2 w01h = { (_Float16)w01, (_Float16)w01 };
            h2 w10h = { (_Float16)w10, (_Float16)w10 };
            h2 w11h = { (_Float16)w11, (_Float16)w11 };

#pragma unroll
            for (int ks = 0; ks < 2; ++ks) {
                union { half8 s8; unsigned u[4]; } A;
#pragma unroll
                for (int q = 0; q < 4; ++q) {
                    HU a00, a01, a10, a11, res;
                    a00.u = g00[ks].a[q]; a01.u = g01[ks].a[q];
                    a10.u = g10[ks].a[q]; a11.u = g11[ks].a[q];
                    h2 acc = a00.h * w00h;
                    acc = a01.h * w01h + acc;
                    acc = a10.h * w10h + acc;
                    acc = a11.h * w11h + acc;
                    res.h = acc;
                    A.u[q] = res.u;
                }
                if (s == 0) {
                    if (ks == 0) {
                        ac00 = __builtin_amdgcn_mfma_f32_16x16x32_f16(A.s8, B00, ac00, 0, 0, 0);
                        ac01 = __builtin_amdgcn_mfma_f32_16x16x32_f16(A.s8, B01, ac01, 0, 0, 0);
                        ac02 = __builtin_amdgcn_mfma_f32_16x16x32_f16(A.s8, B02, ac02, 0, 0, 0);
                        ac03 = __builtin_amdgcn_mfma_f32_16x16x32_f16(A.s8, B03, ac03, 0, 0, 0);
                    } else {
                        ac00 = __builtin_amdgcn_mfma_f32_16x16x32_f16(A.s8, B10, ac00, 0, 0, 0);
                        ac01 = __builtin_amdgcn_mfma_f32_16x16x32_f16(A.s8, B11, ac01, 0, 0, 0);
                        ac02 = __builtin_amdgcn_mfma_f32_16x16x32_f16(A.s8, B12, ac02, 0, 0, 0);
                        ac03 = __builtin_amdgcn_mfma_f32_16x16x32_f16(A.s8, B13, ac03, 0, 0, 0);
                    }
                } else {
                    if (ks == 0) {
                        ac10 = __builtin_amdgcn_mfma_f32_16x16x32_f16(A.s8, B00, ac10, 0, 0, 0);
                        ac11 = __builtin_amdgcn_mfma_f32_16x16x32_f16(A.s8, B01, ac11, 0, 0, 0);
                        ac12 = __builtin_amdgcn_mfma_f32_16x16x32_f16(A.s8, B02, ac12, 0, 0, 0);
                        ac13 = __builtin_amdgcn_mfma_f32_16x16x32_f16(A.s8, B03, ac13, 0, 0, 0);
                    } else {
                        ac10 = __builtin_amdgcn_mfma_f32_16x16x32_f16(A.s8, B10, ac10, 0, 0, 0);
                        ac11 = __builtin_amdgcn_mfma_f32_16x16x32_f16(A.s8, B11, ac11, 0, 0, 0);
                        ac12 = __builtin_amdgcn_mfma_f32_16x16x32_f16(A.s8, B12, ac12, 0, 0, 0);
                        ac13 = __builtin_amdgcn_mfma_f32_16x16x32_f16(A.s8, B13, ac13, 0, 0, 0);
                    }
                }
            }
        }
    }

    um0 = fminf(fmaxf(64.f * um0, 0.f), 1.f);
    um1 = fminf(fmaxf(64.f * um1, 0.f), 1.f);
    if (lane < 16) {
        upd[(size_t)b * HWSZ + (ib + 0) * WW + jw + lane] = um0;
        upd[(size_t)b * HWSZ + (ib + 1) * WW + jw + lane] = um1;
    }

    int oc = lane & 15;
    int pr0 = lg * 4;
    float u0[4], u1[4];
#pragma unroll
    for (int rr = 0; rr < 4; ++rr) {
        u0[rr] = __shfl(um0, pr0 + rr, 64);
        u1[rr] = __shfl(um1, pr0 + rr, 64);
    }

    // ---- Phase 3: transpose epilogue through LDS (reuse xsm), coalesced NCHW stores ----
    __syncthreads();
    float* outsm = (float*)xsm;      // [128 px][stride 66] = 33,792 B
#define STORE_NT(ACC, NT, S, U)                                               \
    {                                                                         \
        float bo = bias[(NT) * 16 + oc];                                      \
        _Pragma("unroll")                                                     \
        for (int rr = 0; rr < 4; ++rr) {                                      \
            int px = (S) * 64 + w * 16 + pr0 + rr;                            \
            outsm[px * 66 + (NT) * 16 + oc] = (ACC[rr] + bo) * U[rr];         \
        }                                                                     \
    }
    STORE_NT(ac00, 0, 0, u0) STORE_NT(ac01, 1, 0, u0)
    STORE_NT(ac02, 2, 0, u0) STORE_NT(ac03, 3, 0, u0)
    STORE_NT(ac10, 0, 1, u1) STORE_NT(ac11, 1, 1, u1)
    STORE_NT(ac12, 2, 1, u1) STORE_NT(ac13, 3, 1, u1)
#undef STORE_NT
    __syncthreads();
    {
        int ch = threadIdx.x & 63, q = threadIdx.x >> 6;
        int row = q >> 1, colh = (q & 1) * 32;
        float* dst = out + ((size_t)(b * 64 + ch)) * HWSZ + (ib + row) * WW + j0b + colh;
#pragma unroll
        for (int gq = 0; gq < 8; ++gq) {
            int px = q * 32 + gq * 4;
            float4 v = { outsm[(px + 0) * 66 + ch], outsm[(px + 1) * 66 + ch],
                         outsm[(px + 2) * 66 + ch], outsm[(px + 3) * 66 + ch] };
            *(float4*)(dst + gq * 4) = v;
        }
    }
}

extern "C" void kernel_launch(void* const* d_in, const int* in_sizes, int n_in,
                              void* d_out, int out_size, void* d_ws, size_t ws_size,
                              hipStream_t stream) {
    const float* input    = (const float*)d_in[0];
    const float* mask_in  = (const float*)d_in[1];
    const float* weight   = (const float*)d_in[2];
    const float* bias     = (const float*)d_in[3];
    const float* offset_w = (const float*)d_in[4];
    const float* offset_b = (const float*)d_in[5];
    const float* mask_w   = (const float*)d_in[6];
    const float* mask_b   = (const float*)d_in[7];

    float* out = (float*)d_out;
    float* upd = out + (size_t)NB * 64 * HWSZ;

    short* wd2 = (short*)d_ws;                 // 36,864 f16
    short* wc2 = wd2 + 36864;                  // 27,648 f16
    short* xt2 = wc2 + 27648;                  // 4*12*16384*8 f16 = 12.6 MB

    hipLaunchKernelGGL(prep_kernel, dim3(1168), dim3(256), 0, stream,
                       input, mask_in, weight, offset_w, mask_w, xt2, wd2, wc2);
    hipLaunchKernelGGL(fused_conv_deform, dim3(512), dim3(256), 0, stream,
                       xt2, mask_in, (const half8*)wc2, (const half8*)wd2,
                       offset_b, mask_b, bias, out, upd);
}

// Round 16
// 39.740 us; speedup vs baseline: 1.0795x; 1.0795x over previous
//
#include <hip/hip_runtime.h>

#define HH 128
#define WW 128
#define HWSZ (HH*WW)
#define NB 4
#define KK 9
#define PS (HWSZ*8)          // plane stride in shorts: 16384 px * 8 ch
#define IMS (12*PS)          // image stride in shorts: 12 channel-blocks
#define TROWS 6
#define TCOLS 68
#define TPX (TROWS*TCOLS)    // 408 pixels per staged plane

typedef _Float16 half8 __attribute__((ext_vector_type(8)));
typedef _Float16 h2    __attribute__((ext_vector_type(2)));
typedef float f32x4    __attribute__((ext_vector_type(4)));

union U4 { uint4 v; unsigned a[4]; };
union HU { unsigned u; h2 h; };

__device__ __forceinline__ short f2h(float f) {
    union { _Float16 h; short s; } u; u.h = (_Float16)f; return u.s;
}
__device__ __forceinline__ void gl_lds16(const short* g, short* l) {
    __builtin_amdgcn_global_load_lds(
        (const __attribute__((address_space(1))) void*)g,
        (__attribute__((address_space(3))) void*)l, 16, 0, 0);
}
__device__ __forceinline__ void gl_lds4(const float* g, float* l) {
    __builtin_amdgcn_global_load_lds(
        (const __attribute__((address_space(1))) void*)g,
        (__attribute__((address_space(3))) void*)l, 4, 0, 0);
}

// ---------------- prep: channel-block-planar f16 transpose + weight repack ----------------
__global__ __launch_bounds__(256) void prep_kernel(
    const float* __restrict__ input,
    const float* __restrict__ mask_in,
    const float* __restrict__ weight,
    const float* __restrict__ offset_w,
    const float* __restrict__ mask_w,
    short* __restrict__ xt2,
    short* __restrict__ wd2,
    short* __restrict__ wc2)
{
    __shared__ short lds[64 * 104];
    int bid = blockIdx.x;
    if (bid < 1024) {
        int wg = ((bid & 7) << 7) | (bid >> 3);
        int g0 = wg * 64;
        int b  = g0 >> 14;
        int p0 = g0 & (HWSZ - 1);
        int px = threadIdx.x & 63;
        int cq = threadIdx.x >> 6;
#pragma unroll
        for (int it = 0; it < 24; ++it) {
            int c = it * 4 + cq;
            float v;
            if (c < 64)       v = input[((size_t)(b * 64 + c)) * HWSZ + p0 + px];
            else if (c == 64) v = mask_in[(size_t)b * HWSZ + p0 + px];
            else              v = 0.f;
            lds[px * 104 + c] = f2h(v);
        }
        __syncthreads();
#pragma unroll
        for (int it = 0; it < 3; ++it) {
            int idx = it * 256 + threadIdx.x;
            if (idx < 768) {
                int ppx = idx / 12, cb = idx - ppx * 12;
                uint4 v = *(const uint4*)&lds[ppx * 104 + cb * 8];
                *(uint4*)&xt2[(size_t)b * IMS + (size_t)cb * PS + (size_t)(p0 + ppx) * 8] = v;
            }
        }
    } else {
        int idx = (bid - 1024) * 256 + threadIdx.x;
        if (idx < 36864) {
            int j = idx & 7, l = (idx >> 3) & 63, f = idx >> 9;
            int nt = f & 3, t9 = f >> 2;
            int k = t9 % 9, ks = t9 / 9;
            int o = nt * 16 + (l & 15);
            int c = ks * 32 + ((l >> 4) & 3) * 8 + j;
            wd2[idx] = f2h(weight[(o * 64 + c) * 9 + k]);
        }
        if (idx < 27648) {
            int j = idx & 7, l = (idx >> 3) & 63, f = idx >> 9;
            int nt = f & 1, t9 = f >> 1;
            int k = t9 % 9, ks = t9 / 9;
            int o = nt * 16 + (l & 15);
            int c = ks * 32 + ((l >> 4) & 3) * 8 + j;
            float v = 0.f;
            if (c <= 64) {
                if (o < 18)      v = offset_w[(o * 65 + c) * 9 + k];
                else if (o < 27) v = mask_w[((o - 18) * 65 + c) * 9 + k];
            }
            wc2[idx] = f2h(v);
        }
    }
}

// ---------------- fused conv + deform: 128 px/block (2 rows x 64 cols), 32 px/wave ----------------
__global__ __launch_bounds__(256, 2) void fused_conv_deform(
    const short* __restrict__ xt2, const float* __restrict__ mask_in,
    const half8* __restrict__ wc, const half8* __restrict__ wd,
    const float* __restrict__ offset_b, const float* __restrict__ mask_b,
    const float* __restrict__ bias,
    float* __restrict__ out, float* __restrict__ upd)
{
    __shared__ short xsm[8 * TPX * 8];   // 52,224 B (reused as outsm in epilogue)
    __shared__ float msm[TPX];           //  1,632 B
    __shared__ short offsm[128 * 32];    //  8,192 B f16 (slots 0..26 used)

    int bid = blockIdx.x;
    int wg = ((bid & 7) << 6) | (bid >> 3);   // 512 blocks, XCD bands of 64
    int w = threadIdx.x >> 6, lane = threadIdx.x & 63;
    int r = lane & 15, lg = lane >> 4;
    int b = wg >> 7;
    int rem = wg & 127;
    int ib = (rem >> 1) * 2;          // row pair base
    int j0b = (rem & 1) * 64;         // column half
    int jw = j0b + w * 16;            // wave's column base
    int jj0 = jw + r;                 // this lane's column

    const short* xg = xt2 + (size_t)b * IMS;
    const short* xq = xg + (size_t)lg * PS;   // fallback base (ks0 plane lg)
    const float* mb = mask_in + (size_t)b * HWSZ;

    // ---- Phase 0: async-stage tile (8 planes x 6x68 x 8ch f16) + mask (6x68 f32) ----
#pragma unroll
    for (int cb = 0; cb < 8; ++cb) {
#pragma unroll
        for (int it = 0; it < 2; ++it) {
            int idx = it * 256 + threadIdx.x;
            if (idx < TPX) {
                int tr = idx / TCOLS, tc = idx - tr * TCOLS;
                int rg = min(max(ib - 2 + tr, 0), HH - 1);
                int cg = min(max(j0b - 2 + tc, 0), WW - 1);
                gl_lds16(&xg[(size_t)cb * PS + (size_t)(rg * WW + cg) * 8],
                         &xsm[(cb * TPX + idx) * 8]);
            }
        }
    }
#pragma unroll
    for (int it = 0; it < 2; ++it) {
        int idx = it * 256 + threadIdx.x;
        if (idx < TPX) {
            int tr = idx / TCOLS, tc = idx - tr * TCOLS;
            int rg = min(max(ib - 2 + tr, 0), HH - 1);
            int cg = min(max(j0b - 2 + tc, 0), WW - 1);
            gl_lds4(&mb[rg * WW + cg], &msm[idx]);
        }
    }
    asm volatile("s_waitcnt vmcnt(0)" ::: "memory");
    __syncthreads();

    // ---- Phase 1: offset/mask conv, A from LDS tile, 2 pixel-sets per wave ----
    {
        f32x4 ca00 = {0,0,0,0}, ca01 = {0,0,0,0};   // set0 nt0/nt1
        f32x4 ca10 = {0,0,0,0}, ca11 = {0,0,0,0};   // set1
#pragma unroll
        for (int t = 0; t < 9; ++t) {
            int dr = t / 3 - 1, dc = t % 3 - 1;
            const half8* wck = wc + (t * 2) * 64 + lane;
            half8 Bk0n0 = wck[0],        Bk0n1 = wck[64];
            half8 Bk1n0 = wck[9*2*64],   Bk1n1 = wck[9*2*64 + 64];
            half8 Bk2n0 = wck[18*2*64],  Bk2n1 = wck[18*2*64 + 64];
#pragma unroll
            for (int s = 0; s < 2; ++s) {
                int ii = ib + s + dr, jj = jj0 + dc;
                bool valid = ((unsigned)ii < HH) && ((unsigned)jj < WW);
                int tr = ii - (ib - 2), tc = jj - (j0b - 2);
                int loff = (tr * TCOLS + tc) * 8;
                union { half8 s8; uint4 u; } A0, A1, A2;
                A0.u = *(const uint4*)&xsm[lg * (TPX * 8) + loff];
                A1.u = *(const uint4*)&xsm[(4 + lg) * (TPX * 8) + loff];
                if (!valid) {
                    A0.u.x = 0; A0.u.y = 0; A0.u.z = 0; A0.u.w = 0;
                    A1.u.x = 0; A1.u.y = 0; A1.u.z = 0; A1.u.w = 0;
                }
                unsigned am = (valid && lg == 0)
                            ? (unsigned)(unsigned short)f2h(msm[tr * TCOLS + tc]) : 0u;
                A2.u.x = am; A2.u.y = 0; A2.u.z = 0; A2.u.w = 0;
                if (s == 0) {
                    ca00 = __builtin_amdgcn_mfma_f32_16x16x32_f16(A0.s8, Bk0n0, ca00, 0, 0, 0);
                    ca01 = __builtin_amdgcn_mfma_f32_16x16x32_f16(A0.s8, Bk0n1, ca01, 0, 0, 0);
                    ca00 = __builtin_amdgcn_mfma_f32_16x16x32_f16(A1.s8, Bk1n0, ca00, 0, 0, 0);
                    ca01 = __builtin_amdgcn_mfma_f32_16x16x32_f16(A1.s8, Bk1n1, ca01, 0, 0, 0);
                    ca00 = __builtin_amdgcn_mfma_f32_16x16x32_f16(A2.s8, Bk2n0, ca00, 0, 0, 0);
                    ca01 = __builtin_amdgcn_mfma_f32_16x16x32_f16(A2.s8, Bk2n1, ca01, 0, 0, 0);
                } else {
                    ca10 = __builtin_amdgcn_mfma_f32_16x16x32_f16(A0.s8, Bk0n0, ca10, 0, 0, 0);
                    ca11 = __builtin_amdgcn_mfma_f32_16x16x32_f16(A0.s8, Bk0n1, ca11, 0, 0, 0);
                    ca10 = __builtin_amdgcn_mfma_f32_16x16x32_f16(A1.s8, Bk1n0, ca10, 0, 0, 0);
                    ca11 = __builtin_amdgcn_mfma_f32_16x16x32_f16(A1.s8, Bk1n1, ca11, 0, 0, 0);
                    ca10 = __builtin_amdgcn_mfma_f32_16x16x32_f16(A2.s8, Bk2n0, ca10, 0, 0, 0);
                    ca11 = __builtin_amdgcn_mfma_f32_16x16x32_f16(A2.s8, Bk2n1, ca11, 0, 0, 0);
                }
            }
        }
        int oc = lane & 15, pr0 = lg * 4;
#pragma unroll
        for (int s = 0; s < 2; ++s) {
            const f32x4& c0 = s ? ca10 : ca00;
            const f32x4& c1 = s ? ca11 : ca01;
#pragma unroll
            for (int rr = 0; rr < 4; ++rr) {
                int px = s * 64 + w * 16 + pr0 + rr;
                offsm[px * 32 + oc] = f2h(c0[rr] + offset_b[oc]);
                int oc2 = 16 + oc;
                if (oc2 < 18) {
                    offsm[px * 32 + oc2] = f2h(c1[rr] + offset_b[oc2]);
                } else if (oc2 < 27) {
                    float z = c1[rr] + mask_b[oc2 - 18];
                    offsm[px * 32 + oc2] = f2h(1.f / (1.f + __expf(-z)));
                }
            }
        }
    }
    __syncthreads();

    // ---- Phase 2: deformable conv, 2 pixel-sets per wave, B reused across sets ----
    float ov0[28], ov1[28];
#pragma unroll
    for (int s = 0; s < 2; ++s) {
        int px = s * 64 + w * 16 + r;
        float* ov = s ? ov1 : ov0;
        const U4* op = (const U4*)&offsm[px * 32];
#pragma unroll
        for (int q4 = 0; q4 < 4; ++q4) {
            U4 t = op[q4];
#pragma unroll
            for (int e = 0; e < 4; ++e) {
                int base = q4 * 8 + e * 2;
                if (base < 28) {
                    HU hu; hu.u = t.a[e];
                    ov[base] = (float)hu.h[0];
                    ov[base + 1] = (float)hu.h[1];
                }
            }
        }
    }

    f32x4 ac00 = {0,0,0,0}, ac01 = {0,0,0,0}, ac02 = {0,0,0,0}, ac03 = {0,0,0,0};
    f32x4 ac10 = {0,0,0,0}, ac11 = {0,0,0,0}, ac12 = {0,0,0,0}, ac13 = {0,0,0,0};
    float um0 = 0.f, um1 = 0.f;

#pragma unroll
    for (int k = 0; k < KK; ++k) {
        const half8* w0 = wd + ((0 * 9 + k) * 4) * 64 + lane;
        const half8* w1 = wd + ((1 * 9 + k) * 4) * 64 + lane;
        half8 B00 = w0[0], B01 = w0[64], B02 = w0[128], B03 = w0[192];
        half8 B10 = w1[0], B11 = w1[64], B12 = w1[128], B13 = w1[192];

#pragma unroll
        for (int s = 0; s < 2; ++s) {
            const float* ov = s ? ov1 : ov0;
            int i = ib + s, j = jj0;
            float dy = ov[2*k], dx = ov[2*k+1], m = ov[18+k];
            float py  = dy + (float)(k / 3 + i - 1);
            float pxx = dx + (float)(k % 3 + j - 1);
            float fy = floorf(py), fx = floorf(pxx);
            float wy = py - fy, wx = pxx - fx;
            int y0 = (int)fy, x0 = (int)fx;
            int y1 = y0 + 1, x1 = x0 + 1;
            bool vy0 = (unsigned)y0 < HH, vy1 = (unsigned)y1 < HH;
            bool vx0 = (unsigned)x0 < WW, vx1 = (unsigned)x1 < WW;
            int yc0 = min(max(y0, 0), HH - 1), yc1 = min(max(y1, 0), HH - 1);
            int xc0 = min(max(x0, 0), WW - 1), xc1 = min(max(x1, 0), WW - 1);
            float r00 = (vy0 && vx0) ? (1.f - wy) * (1.f - wx) : 0.f;
            float r01 = (vy0 && vx1) ? (1.f - wy) * wx : 0.f;
            float r10 = (vy1 && vx0) ? wy * (1.f - wx) : 0.f;
            float r11 = (vy1 && vx1) ? wy * wx : 0.f;

            int tr0 = yc0 - (ib - 2), tr1 = yc1 - (ib - 2);
            int tc0 = xc0 - (j0b - 2), tc1 = xc1 - (j0b - 2);
            bool in00 = ((unsigned)tr0 < (unsigned)TROWS) & ((unsigned)tc0 < (unsigned)TCOLS);
            bool in01 = ((unsigned)tr0 < (unsigned)TROWS) & ((unsigned)tc1 < (unsigned)TCOLS);
            bool in10 = ((unsigned)tr1 < (unsigned)TROWS) & ((unsigned)tc0 < (unsigned)TCOLS);
            bool in11 = ((unsigned)tr1 < (unsigned)TROWS) & ((unsigned)tc1 < (unsigned)TCOLS);
            int trc0 = min(max(tr0, 0), TROWS - 1), trc1 = min(max(tr1, 0), TROWS - 1);
            int tcc0 = min(max(tc0, 0), TCOLS - 1), tcc1 = min(max(tc1, 0), TCOLS - 1);
            int l00 = trc0 * TCOLS + tcc0, l01 = trc0 * TCOLS + tcc1;
            int l10 = trc1 * TCOLS + tcc0, l11 = trc1 * TCOLS + tcc1;

            U4 g00[2], g01[2], g10[2], g11[2];
#pragma unroll
            for (int ks = 0; ks < 2; ++ks) {
                const short* xs = xsm + (size_t)(ks * 4 + lg) * (TPX * 8);
                g00[ks].v = *(const uint4*)(xs + l00 * 8);
                g01[ks].v = *(const uint4*)(xs + l01 * 8);
                g10[ks].v = *(const uint4*)(xs + l10 * 8);
                g11[ks].v = *(const uint4*)(xs + l11 * 8);
            }
            float m00 = msm[l00], m01 = msm[l01], m10 = msm[l10], m11 = msm[l11];

            if (!__all(in00 & in01 & in10 & in11)) {
                int p00 = yc0 * WW + xc0, p01 = yc0 * WW + xc1;
                int p10 = yc1 * WW + xc0, p11 = yc1 * WW + xc1;
                if (!in00) {
                    g00[0].v = *(const uint4*)(xq + (size_t)p00 * 8);
                    g00[1].v = *(const uint4*)(xq + 4 * PS + (size_t)p00 * 8);
                    m00 = mb[p00];
                }
                if (!in01) {
                    g01[0].v = *(const uint4*)(xq + (size_t)p01 * 8);
                    g01[1].v = *(const uint4*)(xq + 4 * PS + (size_t)p01 * 8);
                    m01 = mb[p01];
                }
                if (!in10) {
                    g10[0].v = *(const uint4*)(xq + (size_t)p10 * 8);
                    g10[1].v = *(const uint4*)(xq + 4 * PS + (size_t)p10 * 8);
                    m10 = mb[p10];
                }
                if (!in11) {
                    g11[0].v = *(const uint4*)(xq + (size_t)p11 * 8);
                    g11[1].v = *(const uint4*)(xq + 4 * PS + (size_t)p11 * 8);
                    m11 = mb[p11];
                }
            }

            float umv = r00 * m00 + r01 * m01 + r10 * m10 + r11 * m11;
            if (s == 0) um0 += umv; else um1 += umv;

            float w00 = r00 * m, w01 = r01 * m, w10 = r10 * m, w11 = r11 * m;
            h2 w00h = { (_Float16)w00, (_Float16)w00 };
            h2 w01h = { (_Float16)w01, (_Float16)w01 };
            h2 w10h = { (_Float16)w10, (_Float16)w10 };
            h2 w11h = { (_Float16)w11, (_Float16)w11 };

#pragma unroll
            for (int ks = 0; ks < 2; ++ks) {
                union { half8 s8; unsigned u[4]; } A;
#pragma unroll
                for (int q = 0; q < 4; ++q) {
                    HU a00, a01, a10, a11, res;
                    a00.u = g00[ks].a[q]; a01.u = g01[ks].a[q];
                    a10.u = g10[ks].a[q]; a11.u = g11[ks].a[q];
                    h2 acc = a00.h * w00h;
                    acc = a01.h * w01h + acc;
                    acc = a10.h * w10h + acc;
                    acc = a11.h * w11h + acc;
                    res.h = acc;
                    A.u[q] = res.u;
                }
                if (s == 0) {
                    if (ks == 0) {
                        ac00 = __builtin_amdgcn_mfma_f32_16x16x32_f16(A.s8, B00, ac00, 0, 0, 0);
                        ac01 = __builtin_amdgcn_mfma_f32_16x16x32_f16(A.s8, B01, ac01, 0, 0, 0);
                        ac02 = __builtin_amdgcn_mfma_f32_16x16x32_f16(A.s8, B02, ac02, 0, 0, 0);
                        ac03 = __builtin_amdgcn_mfma_f32_16x16x32_f16(A.s8, B03, ac03, 0, 0, 0);
                    } else {
                        ac00 = __builtin_amdgcn_mfma_f32_16x16x32_f16(A.s8, B10, ac00, 0, 0, 0);
                        ac01 = __builtin_amdgcn_mfma_f32_16x16x32_f16(A.s8, B11, ac01, 0, 0, 0);
                        ac02 = __builtin_amdgcn_mfma_f32_16x16x32_f16(A.s8, B12, ac02, 0, 0, 0);
                        ac03 = __builtin_amdgcn_mfma_f32_16x16x32_f16(A.s8, B13, ac03, 0, 0, 0);
                    }
                } else {
                    if (ks == 0) {
                        ac10 = __builtin_amdgcn_mfma_f32_16x16x32_f16(A.s8, B00, ac10, 0, 0, 0);
                        ac11 = __builtin_amdgcn_mfma_f32_16x16x32_f16(A.s8, B01, ac11, 0, 0, 0);
                        ac12 = __builtin_amdgcn_mfma_f32_16x16x32_f16(A.s8, B02, ac12, 0, 0, 0);
                        ac13 = __builtin_amdgcn_mfma_f32_16x16x32_f16(A.s8, B03, ac13, 0, 0, 0);
                    } else {
                        ac10 = __builtin_amdgcn_mfma_f32_16x16x32_f16(A.s8, B10, ac10, 0, 0, 0);
                        ac11 = __builtin_amdgcn_mfma_f32_16x16x32_f16(A.s8, B11, ac11, 0, 0, 0);
                        ac12 = __builtin_amdgcn_mfma_f32_16x16x32_f16(A.s8, B12, ac12, 0, 0, 0);
                        ac13 = __builtin_amdgcn_mfma_f32_16x16x32_f16(A.s8, B13, ac13, 0, 0, 0);
                    }
                }
            }
        }
    }

    um0 = fminf(fmaxf(64.f * um0, 0.f), 1.f);
    um1 = fminf(fmaxf(64.f * um1, 0.f), 1.f);
    if (lane < 16) {
        upd[(size_t)b * HWSZ + (ib + 0) * WW + jw + lane] = um0;
        upd[(size_t)b * HWSZ + (ib + 1) * WW + jw + lane] = um1;
    }

    int oc = lane & 15;
    int pr0 = lg * 4;
    float u0[4], u1[4];
#pragma unroll
    for (int rr = 0; rr < 4; ++rr) {
        u0[rr] = __shfl(um0, pr0 + rr, 64);
        u1[rr] = __shfl(um1, pr0 + rr, 64);
    }

    // ---- Phase 3: transpose epilogue through LDS (reuse xsm), coalesced NCHW stores ----
    __syncthreads();
    float* outsm = (float*)xsm;      // [128 px][stride 65] = 33,280 B
#define STORE_NT(ACC, NT, S, U)                                               \
    {                                                                         \
        float bo = bias[(NT) * 16 + oc];                                      \
        _Pragma("unroll")                                                     \
        for (int rr = 0; rr < 4; ++rr) {                                      \
            int px = (S) * 64 + w * 16 + pr0 + rr;                            \
            outsm[px * 65 + (NT) * 16 + oc] = (ACC[rr] + bo) * U[rr];         \
        }                                                                     \
    }
    STORE_NT(ac00, 0, 0, u0) STORE_NT(ac01, 1, 0, u0)
    STORE_NT(ac02, 2, 0, u0) STORE_NT(ac03, 3, 0, u0)
    STORE_NT(ac10, 0, 1, u1) STORE_NT(ac11, 1, 1, u1)
    STORE_NT(ac12, 2, 1, u1) STORE_NT(ac13, 3, 1, u1)
#undef STORE_NT
    __syncthreads();
    {
        int ch = threadIdx.x >> 2, q = threadIdx.x & 3;   // q: 32-px chunk
        int row = q >> 1, colh = (q & 1) * 32;
        float* dst = out + ((size_t)(b * 64 + ch)) * HWSZ + (ib + row) * WW + j0b + colh;
#pragma unroll
        for (int gq = 0; gq < 8; ++gq) {
            int px = q * 32 + gq * 4;
            float4 v = { outsm[(px + 0) * 65 + ch], outsm[(px + 1) * 65 + ch],
                         outsm[(px + 2) * 65 + ch], outsm[(px + 3) * 65 + ch] };
            *(float4*)(dst + gq * 4) = v;
        }
    }
}

extern "C" void kernel_launch(void* const* d_in, const int* in_sizes, int n_in,
                              void* d_out, int out_size, void* d_ws, size_t ws_size,
                              hipStream_t stream) {
    const float* input    = (const float*)d_in[0];
    const float* mask_in  = (const float*)d_in[1];
    const float* weight   = (const float*)d_in[2];
    const float* bias     = (const float*)d_in[3];
    const float* offset_w = (const float*)d_in[4];
    const float* offset_b = (const float*)d_in[5];
    const float* mask_w   = (const float*)d_in[6];
    const float* mask_b   = (const float*)d_in[7];

    float* out = (float*)d_out;
    float* upd = out + (size_t)NB * 64 * HWSZ;

    short* wd2 = (short*)d_ws;                 // 36,864 f16
    short* wc2 = wd2 + 36864;                  // 27,648 f16
    short* xt2 = wc2 + 27648;                  // 4*12*16384*8 f16 = 12.6 MB

    hipLaunchKernelGGL(prep_kernel, dim3(1168), dim3(256), 0, stream,
                       input, mask_in, weight, offset_w, mask_w, xt2, wd2, wc2);
    hipLaunchKernelGGL(fused_conv_deform, dim3(512), dim3(256), 0, stream,
                       xt2, mask_in, (const half8*)wc2, (const half8*)wd2,
                       offset_b, mask_b, bias, out, upd);
}